// Round 5
// baseline (526.747 us; speedup 1.0000x reference)
//
#include <hip/hip_runtime.h>
#include <math.h>

#define LATENT 64
#define N_USERS_C 100000

#define SCAN_T 256
#define SCAN_E 4
#define SCAN_CHUNK (SCAN_T * SCAN_E)   // 1024 elements per block

// ---------- CSR build ----------

__global__ void hist_kernel(const int* __restrict__ row, int* __restrict__ deg, int nnz) {
    int e = blockIdx.x * blockDim.x + threadIdx.x;
    if (e >= nnz) return;
    atomicAdd(&deg[row[e]], 1);
}

// Pass 1: per-block local inclusive scan (pre-offset) into start[i+1]; block totals out.
__global__ void scan1_kernel(const int* __restrict__ deg, int* __restrict__ start,
                             int* __restrict__ blockSums, int n) {
    __shared__ int part[SCAN_T];
    int b = blockIdx.x, t = threadIdx.x;
    int base = b * SCAN_CHUNK + t * SCAN_E;
    int v[SCAN_E];
    int s = 0;
#pragma unroll
    for (int j = 0; j < SCAN_E; j++) {
        int i = base + j;
        v[j] = (i < n) ? deg[i] : 0;
        s += v[j];
    }
    part[t] = s;
    __syncthreads();
    for (int off = 1; off < SCAN_T; off <<= 1) {
        int x = (t >= off) ? part[t - off] : 0;
        __syncthreads();
        part[t] += x;
        __syncthreads();
    }
    int run = (t == 0) ? 0 : part[t - 1];
#pragma unroll
    for (int j = 0; j < SCAN_E; j++) {
        int i = base + j;
        run += v[j];
        if (i < n) start[i + 1] = run;   // local inclusive, pre-offset
    }
    if (t == SCAN_T - 1) blockSums[b] = part[SCAN_T - 1];
}

// Pass 2: exclusive scan of block sums (nb <= 256 fits one block).
__global__ void scan2_kernel(int* __restrict__ blockSums, int nb) {
    __shared__ int part[SCAN_T];
    int t = threadIdx.x;
    part[t] = (t < nb) ? blockSums[t] : 0;
    __syncthreads();
    for (int off = 1; off < SCAN_T; off <<= 1) {
        int x = (t >= off) ? part[t - off] : 0;
        __syncthreads();
        part[t] += x;
        __syncthreads();
    }
    if (t < nb) blockSums[t] = (t == 0) ? 0 : part[t - 1];
}

// Pass 3: add block offsets; also emit cursor[i] = start[i] for the scatter.
__global__ void scan3_kernel(const int* __restrict__ deg, int* __restrict__ start,
                             const int* __restrict__ blockOff, int* __restrict__ cursor,
                             int n) {
    int i = blockIdx.x * blockDim.x + threadIdx.x;
    if (i >= n) return;
    int s = start[i + 1] + blockOff[i / SCAN_CHUNK];
    start[i + 1] = s;
    cursor[i] = s - deg[i];
    if (i == 0) start[0] = 0;
}

// d_inv[i] = (deg[i] + 1e-9)^(-1/2), matching the reference's vals construction.
__global__ void dinv_kernel(const int* __restrict__ deg, float* __restrict__ dinv, int n) {
    int i = blockIdx.x * blockDim.x + threadIdx.x;
    if (i >= n) return;
    dinv[i] = 1.0f / sqrtf((float)deg[i] + 1e-9f);
}

// Scatter cols into CSR order, restricted to rows in [lo,hi).
// Range-passing keeps the destination region (~1.2MB) + cursors (~150KB)
// resident in every XCD's L2, so 4B random stores coalesce into full-line
// writebacks instead of thrashing (R3: WRITE_SIZE 79MB for a 9.6MB region).
__global__ void scatter_range(const int* __restrict__ row, const int* __restrict__ col,
                              int* __restrict__ cursor, int* __restrict__ colsCSR,
                              int nnz, int lo, int hi) {
    int e = blockIdx.x * blockDim.x + threadIdx.x;
    if (e >= nnz) return;
    int r = row[e];
    if (r < lo || r >= hi) return;
    int p = atomicAdd(&cursor[r], 1);
    colsCSR[p] = col[e];
}

// ---------- Row-parallel SpMM: one wave per row, lane = dim ----------
// val[e] = d_inv[r]*d_inv[c] recomputed on the fly; d_inv[r] hoisted out of
// the loop. Edge loop chunked by 8 (MLP 8); predicated tail uses w=0 so the
// dummy gather (col 0, hot line) contributes exactly +0.0.

__global__ void spmm_csr(const int* __restrict__ start, const int* __restrict__ cols,
                         const float* __restrict__ dinv,
                         const float* __restrict__ Ein, float* __restrict__ Eout,
                         int nrows) {
    int t = blockIdx.x * blockDim.x + threadIdx.x;
    int r = t >> 6;
    if (r >= nrows) return;
    int d = t & 63;
    int b = start[r];
    int e = start[r + 1];
    float acc = 0.0f;
    for (int k = b; k < e; k += 8) {
        int c[8];
        float w[8];
#pragma unroll
        for (int j = 0; j < 8; j++) {
            int kk = k + j;
            bool valid = (kk < e);
            c[j] = valid ? cols[kk] : 0;        // wave-uniform 4B load
            w[j] = valid ? dinv[c[j]] : 0.0f;   // wave-uniform, 600KB hot table
        }
        float g[8];
#pragma unroll
        for (int j = 0; j < 8; j++) {
            g[j] = Ein[c[j] * LATENT + d];      // 8 independent 256B gathers
        }
#pragma unroll
        for (int j = 0; j < 8; j++) {
            acc += w[j] * g[j];
        }
    }
    Eout[r * LATENT + d] = acc * dinv[r];
}

// ---------- epilogue ----------

__global__ void gather_acc(const int* __restrict__ users, const int* __restrict__ pos,
                           const int* __restrict__ neg, const float* __restrict__ E,
                           float* __restrict__ acc, int batch) {
    int t = blockIdx.x * blockDim.x + threadIdx.x;
    int total = 3 * batch * LATENT;
    if (t >= total) return;
    int d = t & 63;
    int b = t >> 6;
    int g = b / batch;
    int bb = b - g * batch;
    int r = (g == 0) ? users[bb] : (g == 1) ? (N_USERS_C + pos[bb]) : (N_USERS_C + neg[bb]);
    acc[t] += E[r * LATENT + d];
}

__global__ void finalize(const int* __restrict__ users, const int* __restrict__ pos,
                         const int* __restrict__ neg, const float* __restrict__ E0,
                         const float* __restrict__ acc, float* __restrict__ out, int batch) {
    int t = blockIdx.x * blockDim.x + threadIdx.x;
    int total = 3 * batch * LATENT;
    if (t >= total) return;
    int d = t & 63;
    int b = t >> 6;
    int g = b / batch;
    int bb = b - g * batch;
    int r = (g == 0) ? users[bb] : (g == 1) ? (N_USERS_C + pos[bb]) : (N_USERS_C + neg[bb]);
    float e0 = E0[r * LATENT + d];
    out[t] = 0.25f * (e0 + acc[t]);
    out[total + t] = e0;
}

extern "C" void kernel_launch(void* const* d_in, const int* in_sizes, int n_in,
                              void* d_out, int out_size, void* d_ws, size_t ws_size,
                              hipStream_t stream) {
    const int*   users = (const int*)d_in[0];
    const int*   pos   = (const int*)d_in[1];
    const int*   neg   = (const int*)d_in[2];
    const float* E0    = (const float*)d_in[3];
    const int*   row   = (const int*)d_in[4];
    const int*   col   = (const int*)d_in[5];
    float*       out   = (float*)d_out;

    const int batch  = in_sizes[0];          // 4096
    const int nnz    = in_sizes[4];          // 1,200,000
    const int ntotal = in_sizes[3] / LATENT; // 150,000

    auto align256 = [](size_t x) { return (x + 255) & ~(size_t)255; };

    const size_t bufBytes   = align256((size_t)ntotal * LATENT * sizeof(float)); // 38.4 MB
    const size_t colBytes   = align256((size_t)nnz * sizeof(int));               // 4.8 MB
    const size_t startBytes = align256((size_t)(ntotal + 1) * sizeof(int));
    const size_t curBytes   = align256((size_t)ntotal * sizeof(int));
    const size_t dinvBytes  = align256((size_t)ntotal * sizeof(float));
    const size_t degBytes   = align256((size_t)ntotal * sizeof(int));
    const size_t bsBytes    = align256((size_t)SCAN_T * sizeof(int));
    const size_t accBytes   = align256((size_t)3 * batch * LATENT * sizeof(float));

    char* p = (char*)d_ws;
    float* bufA    = (float*)p;             p += bufBytes;
    float* bufB    = (float*)p;             p += bufBytes;
    int*   colsCSR = (int*)p;               p += colBytes;
    int*   startA  = (int*)p;               p += startBytes;
    int*   cursor  = (int*)p;               p += curBytes;
    float* dinv    = (float*)p;             p += dinvBytes;
    int*   bsums   = (int*)p;               p += bsBytes;
    // deg and acc adjacent so one memset zeroes both:
    int*   deg     = (int*)p;               p += degBytes;
    float* acc     = (float*)p;             p += accBytes;

    hipMemsetAsync(deg, 0, degBytes + accBytes, stream);

    const int threads = 256;
    const int eBlocks = (nnz + threads - 1) / threads;
    const int sBlocks = (ntotal * LATENT + threads - 1) / threads;
    const int gBlocks = (3 * batch * LATENT + threads - 1) / threads;
    const int scanBlocks = (ntotal + SCAN_CHUNK - 1) / SCAN_CHUNK;   // 147
    const int nBlocks = (ntotal + threads - 1) / threads;

    // Build CSR
    hist_kernel<<<eBlocks, threads, 0, stream>>>(row, deg, nnz);
    scan1_kernel<<<scanBlocks, SCAN_T, 0, stream>>>(deg, startA, bsums, ntotal);
    scan2_kernel<<<1, SCAN_T, 0, stream>>>(bsums, scanBlocks);
    scan3_kernel<<<nBlocks, threads, 0, stream>>>(deg, startA, bsums, cursor, ntotal);
    dinv_kernel<<<nBlocks, threads, 0, stream>>>(deg, dinv, ntotal);

    // Scatter in 4 row-range passes to keep each pass's write region L2-resident.
    const int NPASS = 4;
    const int q = (ntotal + NPASS - 1) / NPASS;
    for (int ps = 0; ps < NPASS; ps++) {
        int lo = ps * q;
        int hi = lo + q; if (hi > ntotal) hi = ntotal;
        scatter_range<<<eBlocks, threads, 0, stream>>>(row, col, cursor, colsCSR, nnz, lo, hi);
    }

    // Layer 1: E1 = A @ E0 -> bufA
    spmm_csr<<<sBlocks, threads, 0, stream>>>(startA, colsCSR, dinv, E0, bufA, ntotal);
    gather_acc<<<gBlocks, threads, 0, stream>>>(users, pos, neg, bufA, acc, batch);
    // Layer 2: E2 = A @ E1 -> bufB
    spmm_csr<<<sBlocks, threads, 0, stream>>>(startA, colsCSR, dinv, bufA, bufB, ntotal);
    gather_acc<<<gBlocks, threads, 0, stream>>>(users, pos, neg, bufB, acc, batch);
    // Layer 3: E3 = A @ E2 -> bufA
    spmm_csr<<<sBlocks, threads, 0, stream>>>(startA, colsCSR, dinv, bufB, bufA, ntotal);
    gather_acc<<<gBlocks, threads, 0, stream>>>(users, pos, neg, bufA, acc, batch);

    finalize<<<gBlocks, threads, 0, stream>>>(users, pos, neg, E0, acc, out, batch);
}

// Round 6
// 483.546 us; speedup vs baseline: 1.0893x; 1.0893x over previous
//
#include <hip/hip_runtime.h>

#define LATENT 64
#define N_USERS_C 100000

#define SCAN_T 256
#define SCAN_E 4
#define SCAN_CHUNK (SCAN_T * SCAN_E)   // 1024 elements per block

// ---------- CSR build ----------

__global__ void hist_kernel(const int* __restrict__ row, int* __restrict__ deg, int nnz) {
    int e = blockIdx.x * blockDim.x + threadIdx.x;
    if (e >= nnz) return;
    atomicAdd(&deg[row[e]], 1);
}

// Pass 1: per-block local inclusive scan (pre-offset) into start[i+1]; block totals out.
__global__ void scan1_kernel(const int* __restrict__ deg, int* __restrict__ start,
                             int* __restrict__ blockSums, int n) {
    __shared__ int part[SCAN_T];
    int b = blockIdx.x, t = threadIdx.x;
    int base = b * SCAN_CHUNK + t * SCAN_E;
    int v[SCAN_E];
    int s = 0;
#pragma unroll
    for (int j = 0; j < SCAN_E; j++) {
        int i = base + j;
        v[j] = (i < n) ? deg[i] : 0;
        s += v[j];
    }
    part[t] = s;
    __syncthreads();
    for (int off = 1; off < SCAN_T; off <<= 1) {
        int x = (t >= off) ? part[t - off] : 0;
        __syncthreads();
        part[t] += x;
        __syncthreads();
    }
    int run = (t == 0) ? 0 : part[t - 1];
#pragma unroll
    for (int j = 0; j < SCAN_E; j++) {
        int i = base + j;
        run += v[j];
        if (i < n) start[i + 1] = run;   // local inclusive, pre-offset
    }
    if (t == SCAN_T - 1) blockSums[b] = part[SCAN_T - 1];
}

// Pass 2: exclusive scan of block sums (nb <= 256 fits one block).
__global__ void scan2_kernel(int* __restrict__ blockSums, int nb) {
    __shared__ int part[SCAN_T];
    int t = threadIdx.x;
    part[t] = (t < nb) ? blockSums[t] : 0;
    __syncthreads();
    for (int off = 1; off < SCAN_T; off <<= 1) {
        int x = (t >= off) ? part[t - off] : 0;
        __syncthreads();
        part[t] += x;
        __syncthreads();
    }
    if (t < nb) blockSums[t] = (t == 0) ? 0 : part[t - 1];
}

// Pass 3: add block offsets; also emit cursor[i] = start[i] for the scatter.
__global__ void scan3_kernel(const int* __restrict__ deg, int* __restrict__ start,
                             const int* __restrict__ blockOff, int* __restrict__ cursor,
                             int n) {
    int i = blockIdx.x * blockDim.x + threadIdx.x;
    if (i >= n) return;
    int s = start[i + 1] + blockOff[i / SCAN_CHUNK];
    start[i + 1] = s;
    cursor[i] = s - deg[i];
    if (i == 0) start[0] = 0;
}

// Scatter packed {col,val} edges into CSR order, restricted to rows in [lo,hi).
// Range-passing keeps the destination region (~2.4MB) + cursors (~150KB)
// L2-resident so random 8B stores accumulate into full lines before writeback
// (R3 single-pass: WRITE_SIZE 79MB for a 9.6MB region).
__global__ void scatter_range(const int* __restrict__ row, const int* __restrict__ col,
                              const float* __restrict__ vals,
                              int* __restrict__ cursor, int2* __restrict__ edges,
                              int nnz, int lo, int hi) {
    int e = blockIdx.x * blockDim.x + threadIdx.x;
    if (e >= nnz) return;
    int r = row[e];
    if (r < lo || r >= hi) return;
    int p = atomicAdd(&cursor[r], 1);
    edges[p] = make_int2(col[e], __float_as_int(vals[e]));
}

// ---------- Row-parallel SpMM: one wave per row, lane = dim ----------
// Single wave-uniform 8B {col,val} load per edge (no dependent second load —
// R4's dinv recompute cost +16us/dispatch). Edge loop chunked by 8 (MLP 8);
// predicated tail uses val=0 so the dummy gather (col 0) contributes +0.0.

__global__ void spmm_csr(const int* __restrict__ start, const int2* __restrict__ edges,
                         const float* __restrict__ Ein, float* __restrict__ Eout,
                         int nrows) {
    int t = blockIdx.x * blockDim.x + threadIdx.x;
    int r = t >> 6;
    if (r >= nrows) return;
    int d = t & 63;
    int b = start[r];
    int e = start[r + 1];
    float acc = 0.0f;
    for (int k = b; k < e; k += 8) {
        int2 ed[8];
#pragma unroll
        for (int j = 0; j < 8; j++) {
            int kk = k + j;
            ed[j] = (kk < e) ? edges[kk] : make_int2(0, 0);
        }
        float g[8];
#pragma unroll
        for (int j = 0; j < 8; j++) {
            g[j] = Ein[ed[j].x * LATENT + d];   // 8 independent 256B gathers
        }
#pragma unroll
        for (int j = 0; j < 8; j++) {
            acc += __int_as_float(ed[j].y) * g[j];
        }
    }
    Eout[r * LATENT + d] = acc;
}

// ---------- epilogue ----------

__global__ void gather_acc(const int* __restrict__ users, const int* __restrict__ pos,
                           const int* __restrict__ neg, const float* __restrict__ E,
                           float* __restrict__ acc, int batch) {
    int t = blockIdx.x * blockDim.x + threadIdx.x;
    int total = 3 * batch * LATENT;
    if (t >= total) return;
    int d = t & 63;
    int b = t >> 6;
    int g = b / batch;
    int bb = b - g * batch;
    int r = (g == 0) ? users[bb] : (g == 1) ? (N_USERS_C + pos[bb]) : (N_USERS_C + neg[bb]);
    acc[t] += E[r * LATENT + d];
}

__global__ void finalize(const int* __restrict__ users, const int* __restrict__ pos,
                         const int* __restrict__ neg, const float* __restrict__ E0,
                         const float* __restrict__ acc, float* __restrict__ out, int batch) {
    int t = blockIdx.x * blockDim.x + threadIdx.x;
    int total = 3 * batch * LATENT;
    if (t >= total) return;
    int d = t & 63;
    int b = t >> 6;
    int g = b / batch;
    int bb = b - g * batch;
    int r = (g == 0) ? users[bb] : (g == 1) ? (N_USERS_C + pos[bb]) : (N_USERS_C + neg[bb]);
    float e0 = E0[r * LATENT + d];
    out[t] = 0.25f * (e0 + acc[t]);
    out[total + t] = e0;
}

extern "C" void kernel_launch(void* const* d_in, const int* in_sizes, int n_in,
                              void* d_out, int out_size, void* d_ws, size_t ws_size,
                              hipStream_t stream) {
    const int*   users = (const int*)d_in[0];
    const int*   pos   = (const int*)d_in[1];
    const int*   neg   = (const int*)d_in[2];
    const float* E0    = (const float*)d_in[3];
    const int*   row   = (const int*)d_in[4];
    const int*   col   = (const int*)d_in[5];
    const float* vals  = (const float*)d_in[6];
    float*       out   = (float*)d_out;

    const int batch  = in_sizes[0];          // 4096
    const int nnz    = in_sizes[4];          // 1,200,000
    const int ntotal = in_sizes[3] / LATENT; // 150,000

    auto align256 = [](size_t x) { return (x + 255) & ~(size_t)255; };

    const size_t bufBytes   = align256((size_t)ntotal * LATENT * sizeof(float)); // 38.4 MB
    const size_t edgeBytes  = align256((size_t)nnz * sizeof(int2));              // 9.6 MB
    const size_t startBytes = align256((size_t)(ntotal + 1) * sizeof(int));
    const size_t curBytes   = align256((size_t)ntotal * sizeof(int));
    const size_t degBytes   = align256((size_t)ntotal * sizeof(int));
    const size_t bsBytes    = align256((size_t)SCAN_T * sizeof(int));
    const size_t accBytes   = align256((size_t)3 * batch * LATENT * sizeof(float));

    char* p = (char*)d_ws;
    float* bufA    = (float*)p;             p += bufBytes;
    float* bufB    = (float*)p;             p += bufBytes;
    int2*  edges   = (int2*)p;              p += edgeBytes;
    int*   startA  = (int*)p;               p += startBytes;
    int*   cursor  = (int*)p;               p += curBytes;
    int*   bsums   = (int*)p;               p += bsBytes;
    // deg and acc adjacent so one memset zeroes both:
    int*   deg     = (int*)p;               p += degBytes;
    float* acc     = (float*)p;             p += accBytes;

    hipMemsetAsync(deg, 0, degBytes + accBytes, stream);

    const int threads = 256;
    const int eBlocks = (nnz + threads - 1) / threads;
    const int sBlocks = (ntotal * LATENT + threads - 1) / threads;
    const int gBlocks = (3 * batch * LATENT + threads - 1) / threads;
    const int scanBlocks = (ntotal + SCAN_CHUNK - 1) / SCAN_CHUNK;   // 147
    const int nBlocks = (ntotal + threads - 1) / threads;

    // Build CSR
    hist_kernel<<<eBlocks, threads, 0, stream>>>(row, deg, nnz);
    scan1_kernel<<<scanBlocks, SCAN_T, 0, stream>>>(deg, startA, bsums, ntotal);
    scan2_kernel<<<1, SCAN_T, 0, stream>>>(bsums, scanBlocks);
    scan3_kernel<<<nBlocks, threads, 0, stream>>>(deg, startA, bsums, cursor, ntotal);

    // Scatter packed edges in 4 row-range passes (write region L2-resident per pass).
    const int NPASS = 4;
    const int q = (ntotal + NPASS - 1) / NPASS;
    for (int ps = 0; ps < NPASS; ps++) {
        int lo = ps * q;
        int hi = lo + q; if (hi > ntotal) hi = ntotal;
        scatter_range<<<eBlocks, threads, 0, stream>>>(row, col, vals, cursor, edges, nnz, lo, hi);
    }

    // Layer 1: E1 = A @ E0 -> bufA
    spmm_csr<<<sBlocks, threads, 0, stream>>>(startA, edges, E0, bufA, ntotal);
    gather_acc<<<gBlocks, threads, 0, stream>>>(users, pos, neg, bufA, acc, batch);
    // Layer 2: E2 = A @ E1 -> bufB
    spmm_csr<<<sBlocks, threads, 0, stream>>>(startA, edges, bufA, bufB, ntotal);
    gather_acc<<<gBlocks, threads, 0, stream>>>(users, pos, neg, bufB, acc, batch);
    // Layer 3: E3 = A @ E2 -> bufA
    spmm_csr<<<sBlocks, threads, 0, stream>>>(startA, edges, bufB, bufA, ntotal);
    gather_acc<<<gBlocks, threads, 0, stream>>>(users, pos, neg, bufA, acc, batch);

    finalize<<<gBlocks, threads, 0, stream>>>(users, pos, neg, E0, acc, out, batch);
}

// Round 7
// 479.008 us; speedup vs baseline: 1.0997x; 1.0095x over previous
//
#include <hip/hip_runtime.h>
#include <hip/hip_fp16.h>

#define LATENT 64
#define N_USERS_C 100000

#define SCAN_T 256
#define SCAN_E 4
#define SCAN_CHUNK (SCAN_T * SCAN_E)   // 1024 elements per block

// ---------- CSR build ----------

__global__ void hist_kernel(const int* __restrict__ row, int* __restrict__ deg, int nnz) {
    int e = blockIdx.x * blockDim.x + threadIdx.x;
    if (e >= nnz) return;
    atomicAdd(&deg[row[e]], 1);
}

__global__ void scan1_kernel(const int* __restrict__ deg, int* __restrict__ start,
                             int* __restrict__ blockSums, int n) {
    __shared__ int part[SCAN_T];
    int b = blockIdx.x, t = threadIdx.x;
    int base = b * SCAN_CHUNK + t * SCAN_E;
    int v[SCAN_E];
    int s = 0;
#pragma unroll
    for (int j = 0; j < SCAN_E; j++) {
        int i = base + j;
        v[j] = (i < n) ? deg[i] : 0;
        s += v[j];
    }
    part[t] = s;
    __syncthreads();
    for (int off = 1; off < SCAN_T; off <<= 1) {
        int x = (t >= off) ? part[t - off] : 0;
        __syncthreads();
        part[t] += x;
        __syncthreads();
    }
    int run = (t == 0) ? 0 : part[t - 1];
#pragma unroll
    for (int j = 0; j < SCAN_E; j++) {
        int i = base + j;
        run += v[j];
        if (i < n) start[i + 1] = run;
    }
    if (t == SCAN_T - 1) blockSums[b] = part[SCAN_T - 1];
}

__global__ void scan2_kernel(int* __restrict__ blockSums, int nb) {
    __shared__ int part[SCAN_T];
    int t = threadIdx.x;
    part[t] = (t < nb) ? blockSums[t] : 0;
    __syncthreads();
    for (int off = 1; off < SCAN_T; off <<= 1) {
        int x = (t >= off) ? part[t - off] : 0;
        __syncthreads();
        part[t] += x;
        __syncthreads();
    }
    if (t < nb) blockSums[t] = (t == 0) ? 0 : part[t - 1];
}

__global__ void scan3_kernel(const int* __restrict__ deg, int* __restrict__ start,
                             const int* __restrict__ blockOff, int* __restrict__ cursor,
                             int n) {
    int i = blockIdx.x * blockDim.x + threadIdx.x;
    if (i >= n) return;
    int s = start[i + 1] + blockOff[i / SCAN_CHUNK];
    start[i + 1] = s;
    cursor[i] = s - deg[i];
    if (i == 0) start[0] = 0;
}

// Scatter packed {col,val} edges, rows in [lo,hi) only (write region L2-resident).
__global__ void scatter_range(const int* __restrict__ row, const int* __restrict__ col,
                              const float* __restrict__ vals,
                              int* __restrict__ cursor, int2* __restrict__ edges,
                              int nnz, int lo, int hi) {
    int e = blockIdx.x * blockDim.x + threadIdx.x;
    if (e >= nnz) return;
    int r = row[e];
    if (r < lo || r >= hi) return;
    int p = atomicAdd(&cursor[r], 1);
    edges[p] = make_int2(col[e], __float_as_int(vals[e]));
}

// fp32 -> fp16 table conversion, 4 elements/thread.
__global__ void conv_kernel(const float* __restrict__ in, __half* __restrict__ outh, int n4) {
    int i = blockIdx.x * blockDim.x + threadIdx.x;
    if (i >= n4) return;
    float4 v = ((const float4*)in)[i];
    __half2* o = (__half2*)outh;
    o[2 * i]     = __floats2half2_rn(v.x, v.y);
    o[2 * i + 1] = __floats2half2_rn(v.z, v.w);
}

// ---------- Row-parallel SpMM on fp16 tables: one wave per row, lane = dim ----------
// fp32 accumulate; gather is 128B/wave/edge (half of fp32). Edge loop chunked
// by 8 (MLP 8); predicated tail val=0 -> dummy gather contributes +0.0.

__global__ void spmm_csr_h(const int* __restrict__ start, const int2* __restrict__ edges,
                           const __half* __restrict__ Ein, __half* __restrict__ Eout,
                           int nrows) {
    int t = blockIdx.x * blockDim.x + threadIdx.x;
    int r = t >> 6;
    if (r >= nrows) return;
    int d = t & 63;
    int b = start[r];
    int e = start[r + 1];
    float acc = 0.0f;
    for (int k = b; k < e; k += 8) {
        int2 ed[8];
#pragma unroll
        for (int j = 0; j < 8; j++) {
            int kk = k + j;
            ed[j] = (kk < e) ? edges[kk] : make_int2(0, 0);
        }
        __half g[8];
#pragma unroll
        for (int j = 0; j < 8; j++) {
            g[j] = Ein[ed[j].x * LATENT + d];   // 8 independent 128B gathers
        }
#pragma unroll
        for (int j = 0; j < 8; j++) {
            acc += __int_as_float(ed[j].y) * __half2float(g[j]);
        }
    }
    Eout[r * LATENT + d] = __float2half(acc);
}

// ---------- epilogue ----------

__global__ void gather_acc_h(const int* __restrict__ users, const int* __restrict__ pos,
                             const int* __restrict__ neg, const __half* __restrict__ E,
                             float* __restrict__ acc, int batch) {
    int t = blockIdx.x * blockDim.x + threadIdx.x;
    int total = 3 * batch * LATENT;
    if (t >= total) return;
    int d = t & 63;
    int b = t >> 6;
    int g = b / batch;
    int bb = b - g * batch;
    int r = (g == 0) ? users[bb] : (g == 1) ? (N_USERS_C + pos[bb]) : (N_USERS_C + neg[bb]);
    acc[t] += __half2float(E[r * LATENT + d]);
}

__global__ void finalize(const int* __restrict__ users, const int* __restrict__ pos,
                         const int* __restrict__ neg, const float* __restrict__ E0,
                         const float* __restrict__ acc, float* __restrict__ out, int batch) {
    int t = blockIdx.x * blockDim.x + threadIdx.x;
    int total = 3 * batch * LATENT;
    if (t >= total) return;
    int d = t & 63;
    int b = t >> 6;
    int g = b / batch;
    int bb = b - g * batch;
    int r = (g == 0) ? users[bb] : (g == 1) ? (N_USERS_C + pos[bb]) : (N_USERS_C + neg[bb]);
    float e0 = E0[r * LATENT + d];
    out[t] = 0.25f * (e0 + acc[t]);
    out[total + t] = e0;
}

extern "C" void kernel_launch(void* const* d_in, const int* in_sizes, int n_in,
                              void* d_out, int out_size, void* d_ws, size_t ws_size,
                              hipStream_t stream) {
    const int*   users = (const int*)d_in[0];
    const int*   pos   = (const int*)d_in[1];
    const int*   neg   = (const int*)d_in[2];
    const float* E0    = (const float*)d_in[3];
    const int*   row   = (const int*)d_in[4];
    const int*   col   = (const int*)d_in[5];
    const float* vals  = (const float*)d_in[6];
    float*       out   = (float*)d_out;

    const int batch  = in_sizes[0];          // 4096
    const int nnz    = in_sizes[4];          // 1,200,000
    const int ntotal = in_sizes[3] / LATENT; // 150,000

    auto align256 = [](size_t x) { return (x + 255) & ~(size_t)255; };

    const size_t hbufBytes  = align256((size_t)ntotal * LATENT * sizeof(__half)); // 19.2 MB
    const size_t edgeBytes  = align256((size_t)nnz * sizeof(int2));               // 9.6 MB
    const size_t startBytes = align256((size_t)(ntotal + 1) * sizeof(int));
    const size_t curBytes   = align256((size_t)ntotal * sizeof(int));
    const size_t degBytes   = align256((size_t)ntotal * sizeof(int));
    const size_t bsBytes    = align256((size_t)SCAN_T * sizeof(int));
    const size_t accBytes   = align256((size_t)3 * batch * LATENT * sizeof(float));

    char* p = (char*)d_ws;
    __half* E0h   = (__half*)p;             p += hbufBytes;
    __half* bufA  = (__half*)p;             p += hbufBytes;
    __half* bufB  = (__half*)p;             p += hbufBytes;
    int2*  edges  = (int2*)p;               p += edgeBytes;
    int*   startA = (int*)p;                p += startBytes;
    int*   cursor = (int*)p;                p += curBytes;
    int*   bsums  = (int*)p;                p += bsBytes;
    // deg and acc adjacent so one memset zeroes both:
    int*   deg    = (int*)p;                p += degBytes;
    float* acc    = (float*)p;              p += accBytes;

    hipMemsetAsync(deg, 0, degBytes + accBytes, stream);

    const int threads = 256;
    const int eBlocks = (nnz + threads - 1) / threads;
    const int sBlocks = (ntotal * LATENT + threads - 1) / threads;
    const int gBlocks = (3 * batch * LATENT + threads - 1) / threads;
    const int scanBlocks = (ntotal + SCAN_CHUNK - 1) / SCAN_CHUNK;   // 147
    const int nBlocks = (ntotal + threads - 1) / threads;
    const int n4 = ntotal * LATENT / 4;
    const int cBlocks = (n4 + threads - 1) / threads;

    // Build CSR
    hist_kernel<<<eBlocks, threads, 0, stream>>>(row, deg, nnz);
    scan1_kernel<<<scanBlocks, SCAN_T, 0, stream>>>(deg, startA, bsums, ntotal);
    scan2_kernel<<<1, SCAN_T, 0, stream>>>(bsums, scanBlocks);
    scan3_kernel<<<nBlocks, threads, 0, stream>>>(deg, startA, bsums, cursor, ntotal);

    // Convert E0 -> fp16 table (overlaps nothing; ~10us)
    conv_kernel<<<cBlocks, threads, 0, stream>>>(E0, E0h, n4);

    // Scatter packed edges in 4 row-range passes (write region L2-resident per pass).
    const int NPASS = 4;
    const int q = (ntotal + NPASS - 1) / NPASS;
    for (int ps = 0; ps < NPASS; ps++) {
        int lo = ps * q;
        int hi = lo + q; if (hi > ntotal) hi = ntotal;
        scatter_range<<<eBlocks, threads, 0, stream>>>(row, col, vals, cursor, edges, nnz, lo, hi);
    }

    // Layer 1: E1 = A @ E0h -> bufA
    spmm_csr_h<<<sBlocks, threads, 0, stream>>>(startA, edges, E0h, bufA, ntotal);
    gather_acc_h<<<gBlocks, threads, 0, stream>>>(users, pos, neg, bufA, acc, batch);
    // Layer 2: E2 = A @ E1 -> bufB
    spmm_csr_h<<<sBlocks, threads, 0, stream>>>(startA, edges, bufA, bufB, ntotal);
    gather_acc_h<<<gBlocks, threads, 0, stream>>>(users, pos, neg, bufB, acc, batch);
    // Layer 3: E3 = A @ E2 -> bufA
    spmm_csr_h<<<sBlocks, threads, 0, stream>>>(startA, edges, bufB, bufA, ntotal);
    gather_acc_h<<<gBlocks, threads, 0, stream>>>(users, pos, neg, bufA, acc, batch);

    finalize<<<gBlocks, threads, 0, stream>>>(users, pos, neg, E0, acc, out, batch);
}

// Round 8
// 407.551 us; speedup vs baseline: 1.2925x; 1.1753x over previous
//
#include <hip/hip_runtime.h>
#include <hip/hip_fp16.h>

#define LATENT 64
#define N_USERS_C 100000

#define SCAN_T 256
#define SCAN_E 4
#define SCAN_CHUNK (SCAN_T * SCAN_E)   // 1024 elements per block

// ---------- CSR build ----------

__global__ void hist_kernel(const int* __restrict__ row, int* __restrict__ deg, int nnz) {
    int e = blockIdx.x * blockDim.x + threadIdx.x;
    if (e >= nnz) return;
    atomicAdd(&deg[row[e]], 1);
}

__global__ void scan1_kernel(const int* __restrict__ deg, int* __restrict__ start,
                             int* __restrict__ blockSums, int n) {
    __shared__ int part[SCAN_T];
    int b = blockIdx.x, t = threadIdx.x;
    int base = b * SCAN_CHUNK + t * SCAN_E;
    int v[SCAN_E];
    int s = 0;
#pragma unroll
    for (int j = 0; j < SCAN_E; j++) {
        int i = base + j;
        v[j] = (i < n) ? deg[i] : 0;
        s += v[j];
    }
    part[t] = s;
    __syncthreads();
    for (int off = 1; off < SCAN_T; off <<= 1) {
        int x = (t >= off) ? part[t - off] : 0;
        __syncthreads();
        part[t] += x;
        __syncthreads();
    }
    int run = (t == 0) ? 0 : part[t - 1];
#pragma unroll
    for (int j = 0; j < SCAN_E; j++) {
        int i = base + j;
        run += v[j];
        if (i < n) start[i + 1] = run;
    }
    if (t == SCAN_T - 1) blockSums[b] = part[SCAN_T - 1];
}

__global__ void scan2_kernel(int* __restrict__ blockSums, int nb) {
    __shared__ int part[SCAN_T];
    int t = threadIdx.x;
    part[t] = (t < nb) ? blockSums[t] : 0;
    __syncthreads();
    for (int off = 1; off < SCAN_T; off <<= 1) {
        int x = (t >= off) ? part[t - off] : 0;
        __syncthreads();
        part[t] += x;
        __syncthreads();
    }
    if (t < nb) blockSums[t] = (t == 0) ? 0 : part[t - 1];
}

__global__ void scan3_kernel(const int* __restrict__ deg, int* __restrict__ start,
                             const int* __restrict__ blockOff, int* __restrict__ cursor,
                             int n) {
    int i = blockIdx.x * blockDim.x + threadIdx.x;
    if (i >= n) return;
    int s = start[i + 1] + blockOff[i / SCAN_CHUNK];
    start[i + 1] = s;
    cursor[i] = s - deg[i];
    if (i == 0) start[0] = 0;
}

// Single-pass scatter. The edge store is an 8B atomicExch: fabric atomics
// write payload-only (R0: WRITE == payload exactly), avoiding the
// partial-dirty-line writeback thrash that made plain 8B stores cost 79MB.
__global__ void scatter_kernel(const int* __restrict__ row, const int* __restrict__ col,
                               const float* __restrict__ vals, int* __restrict__ cursor,
                               unsigned long long* __restrict__ edges, int nnz) {
    int e = blockIdx.x * blockDim.x + threadIdx.x;
    if (e >= nnz) return;
    int r = row[e];
    int p = atomicAdd(&cursor[r], 1);
    unsigned long long packed =
        ((unsigned long long)(unsigned)__float_as_int(vals[e]) << 32) | (unsigned)col[e];
    atomicExch(&edges[p], packed);   // low32 = col, high32 = val bits
}

// fp32 -> fp16 table conversion, 4 elements/thread.
__global__ void conv_kernel(const float* __restrict__ in, __half* __restrict__ outh, int n4) {
    int i = blockIdx.x * blockDim.x + threadIdx.x;
    if (i >= n4) return;
    float4 v = ((const float4*)in)[i];
    __half2* o = (__half2*)outh;
    o[2 * i]     = __floats2half2_rn(v.x, v.y);
    o[2 * i + 1] = __floats2half2_rn(v.z, v.w);
}

// ---------- Row-parallel SpMM, 4 edges per vmem instruction ----------
// Wave = 1 row. 4 lane-groups of 16; group g owns edge k+4j+g, lane l in the
// group owns dims 4l..4l+3 (8B ushort4 gather). One gather instruction covers
// 4 edges (R6's version: 1 edge/instr — per-edge instr cost was the limiter).
// fp32 accumulate; cross-group sum via 2 shfl_xor; group 0 stores fp16.

__global__ void spmm_csr_h4(const int* __restrict__ start,
                            const int2* __restrict__ edges,
                            const __half* __restrict__ Ein, __half* __restrict__ Eout,
                            int nrows) {
    int t = blockIdx.x * blockDim.x + threadIdx.x;
    int r = t >> 6;
    if (r >= nrows) return;
    int lane = t & 63;
    int g = lane >> 4;           // edge group 0..3
    int l = lane & 15;           // dims 4l..4l+3
    int b = start[r];
    int e = start[r + 1];
    float a0 = 0.f, a1 = 0.f, a2 = 0.f, a3 = 0.f;
    for (int k = b; k < e; k += 16) {
        int2 ed[4];
#pragma unroll
        for (int j = 0; j < 4; j++) {
            int kk = k + 4 * j + g;
            ed[j] = (kk < e) ? edges[kk] : make_int2(0, 0);   // 4 edges / instr
        }
        ushort4 gv[4];
#pragma unroll
        for (int j = 0; j < 4; j++) {
            gv[j] = *(const ushort4*)(Ein + (size_t)ed[j].x * LATENT + 4 * l);
        }
#pragma unroll
        for (int j = 0; j < 4; j++) {
            float w = __int_as_float(ed[j].y);                // 0.0 for tail dummies
            const __half2* h2 = (const __half2*)&gv[j];
            a0 += w * __low2float(h2[0]);
            a1 += w * __high2float(h2[0]);
            a2 += w * __low2float(h2[1]);
            a3 += w * __high2float(h2[1]);
        }
    }
    // sum the 4 groups (lanes xor 16, 32)
    a0 += __shfl_xor(a0, 16, 64); a0 += __shfl_xor(a0, 32, 64);
    a1 += __shfl_xor(a1, 16, 64); a1 += __shfl_xor(a1, 32, 64);
    a2 += __shfl_xor(a2, 16, 64); a2 += __shfl_xor(a2, 32, 64);
    a3 += __shfl_xor(a3, 16, 64); a3 += __shfl_xor(a3, 32, 64);
    if (g == 0) {
        union { ushort4 u; __half2 h[2]; } o;
        o.h[0] = __floats2half2_rn(a0, a1);
        o.h[1] = __floats2half2_rn(a2, a3);
        *(ushort4*)(Eout + (size_t)r * LATENT + 4 * l) = o.u;
    }
}

// ---------- epilogue: read E0 + all three layer tables directly ----------

__global__ void finalize2(const int* __restrict__ users, const int* __restrict__ pos,
                          const int* __restrict__ neg, const float* __restrict__ E0,
                          const __half* __restrict__ E1, const __half* __restrict__ E2,
                          const __half* __restrict__ E3, float* __restrict__ out, int batch) {
    int t = blockIdx.x * blockDim.x + threadIdx.x;
    int total = 3 * batch * LATENT;
    if (t >= total) return;
    int d = t & 63;
    int b = t >> 6;
    int g = b / batch;
    int bb = b - g * batch;
    int r = (g == 0) ? users[bb] : (g == 1) ? (N_USERS_C + pos[bb]) : (N_USERS_C + neg[bb]);
    size_t idx = (size_t)r * LATENT + d;
    float e0 = E0[idx];
    float s = e0 + __half2float(E1[idx]) + __half2float(E2[idx]) + __half2float(E3[idx]);
    out[t] = 0.25f * s;
    out[total + t] = e0;
}

extern "C" void kernel_launch(void* const* d_in, const int* in_sizes, int n_in,
                              void* d_out, int out_size, void* d_ws, size_t ws_size,
                              hipStream_t stream) {
    const int*   users = (const int*)d_in[0];
    const int*   pos   = (const int*)d_in[1];
    const int*   neg   = (const int*)d_in[2];
    const float* E0    = (const float*)d_in[3];
    const int*   row   = (const int*)d_in[4];
    const int*   col   = (const int*)d_in[5];
    const float* vals  = (const float*)d_in[6];
    float*       out   = (float*)d_out;

    const int batch  = in_sizes[0];          // 4096
    const int nnz    = in_sizes[4];          // 1,200,000
    const int ntotal = in_sizes[3] / LATENT; // 150,000

    auto align256 = [](size_t x) { return (x + 255) & ~(size_t)255; };

    const size_t hbufBytes  = align256((size_t)ntotal * LATENT * sizeof(__half)); // 19.2 MB
    const size_t edgeBytes  = align256((size_t)nnz * sizeof(int2));               // 9.6 MB
    const size_t startBytes = align256((size_t)(ntotal + 1) * sizeof(int));
    const size_t curBytes   = align256((size_t)ntotal * sizeof(int));
    const size_t degBytes   = align256((size_t)ntotal * sizeof(int));
    const size_t bsBytes    = align256((size_t)SCAN_T * sizeof(int));

    char* p = (char*)d_ws;
    __half* E0h   = (__half*)p;             p += hbufBytes;
    __half* bufA  = (__half*)p;             p += hbufBytes;   // E1
    __half* bufB  = (__half*)p;             p += hbufBytes;   // E2
    __half* bufC  = (__half*)p;             p += hbufBytes;   // E3
    int2*  edges  = (int2*)p;               p += edgeBytes;
    int*   startA = (int*)p;                p += startBytes;
    int*   cursor = (int*)p;                p += curBytes;
    int*   bsums  = (int*)p;                p += bsBytes;
    int*   deg    = (int*)p;                p += degBytes;

    hipMemsetAsync(deg, 0, degBytes, stream);

    const int threads = 256;
    const int eBlocks = (nnz + threads - 1) / threads;
    const int sBlocks = (ntotal * LATENT + threads - 1) / threads;
    const int gBlocks = (3 * batch * LATENT + threads - 1) / threads;
    const int scanBlocks = (ntotal + SCAN_CHUNK - 1) / SCAN_CHUNK;   // 147
    const int nBlocks = (ntotal + threads - 1) / threads;
    const int n4 = ntotal * LATENT / 4;
    const int cBlocks = (n4 + threads - 1) / threads;

    // Build CSR
    hist_kernel<<<eBlocks, threads, 0, stream>>>(row, deg, nnz);
    scan1_kernel<<<scanBlocks, SCAN_T, 0, stream>>>(deg, startA, bsums, ntotal);
    scan2_kernel<<<1, SCAN_T, 0, stream>>>(bsums, scanBlocks);
    scan3_kernel<<<nBlocks, threads, 0, stream>>>(deg, startA, bsums, cursor, ntotal);

    // Convert E0 -> fp16 table
    conv_kernel<<<cBlocks, threads, 0, stream>>>(E0, E0h, n4);

    // Single-pass scatter (8B atomic edge stores)
    scatter_kernel<<<eBlocks, threads, 0, stream>>>(row, col, vals, cursor,
                                                    (unsigned long long*)edges, nnz);

    // Three SpMM layers into separate tables
    spmm_csr_h4<<<sBlocks, threads, 0, stream>>>(startA, edges, E0h, bufA, ntotal);
    spmm_csr_h4<<<sBlocks, threads, 0, stream>>>(startA, edges, bufA, bufB, ntotal);
    spmm_csr_h4<<<sBlocks, threads, 0, stream>>>(startA, edges, bufB, bufC, ntotal);

    finalize2<<<gBlocks, threads, 0, stream>>>(users, pos, neg, E0, bufA, bufB, bufC, out, batch);
}